// Round 19
// baseline (378.727 us; speedup 1.0000x reference)
//
#include <hip/hip_runtime.h>
#include <math.h>

typedef __bf16 bf16x8 __attribute__((ext_vector_type(8)));
typedef float  f32x4  __attribute__((ext_vector_type(4)));

// ============================ constants ============================
constexpr int NPTS = 32768;
constexpr long long SOFF = 33554432LL;        // NPTS*64*16, start of scalar outputs

// ---- bf16 fragment region (all weights), element offsets in WBu ----
constexpr int TOT_BF   = 323584;
constexpr int FB_MVB    = 0;
constexpr int FB_MVC    = 36864;
constexpr int FB_MVD    = 73728;
constexpr int FB_S2MV_B = 110592;
constexpr int FB_S2MV_C = 118784;
constexpr int FB_S2MV_D = 135168;
constexpr int FB_S2S_B  = 151552;
constexpr int FB_S2S_C  = 184320;
constexpr int FB_S2S_D  = 249856;
constexpr int FB_MS2S_B = 282624;
constexpr int FB_MS2S_C = 299008;
constexpr int FB_MS2S_D = 315392;
// stage-A frags: hi at [SAW, SAW+SA_TOT), lo at [SAW+SA_TOT, SAW+2*SA_TOT)
constexpr int SAW      = 647168;
constexpr int GAS2_OFF = 73728;
constexpr int SA_TOT   = 90112;

// ---- fused LDS layout (bytes) ----
constexpr int XA_OFF  = 0;        // bf16 [16j][16p][64c] swizzled, 32768
constexpr int HT0_OFF = 32768;    // bf16 [16p][128 rows][8j(0-7)] 16B rows, 32768
// HT1 (j8-15) overlays XA at [0,32768) after phase-A reads complete
constexpr int T1_OFF  = 36864;    // bf16 [16p][256] swizzled, 8192
constexpr int T2_OFF  = 45056;    // 8192
constexpr int C0_OFF  = 53248;    // bf16 [16p][64] swizzled, 2048
constexpr int GT_OFF  = 55296;    // f32 [16p][64o] gate, 4096
constexpr int RED_OFF = 59392;    // 3 x f32[8wv][16p] = 1536 (ends 60928)
constexpr int SA_OFF  = 65536;    // bf16 [16p][128] swizzled, 4096
constexpr int LDS_BYTES = 69632;  // 2 blocks/CU

// ==================== compile-time GA tables (GP/JOIN) ====================
namespace ga {
constexpr int MASK_OF[16] = {0,1,2,4,8,3,5,9,6,10,12,7,11,13,14,15};
constexpr int idx_of_mask(int m){ int r = 0; for(int i=0;i<16;++i) if(MASK_OF[i]==m) r=i; return r; }
constexpr int pcount(int x){ int c=0; while(x){ c += x&1; x >>= 1; } return c; }
constexpr int nswaps(int a,int b){ int s=0; a >>= 1; while(a){ s += pcount(a&b); a >>= 1; } return s; }
constexpr float rsign(int a,int b){ return (nswaps(a,b)&1) ? -1.0f : 1.0f; }
constexpr float dsign(int m){ return rsign(m, 15^m); }
struct Ent { int i, j, k; float s; };
struct GPT { Ent e[192]; };
constexpr GPT make_gp(){
  GPT t{}; int n=0;
  for(int i=0;i<16;++i) for(int j=0;j<16;++j){
    const int a=MASK_OF[i], b=MASK_OF[j];
    if((a & b & 1) != 0) continue;
    t.e[n].i=i; t.e[n].j=j; t.e[n].k=idx_of_mask(a^b); t.e[n].s=rsign(a,b); ++n;
  }
  return t;
}
struct JNT { Ent e[81]; };
constexpr JNT make_jn(){
  JNT t{}; int n=0;
  for(int i=0;i<16;++i) for(int j=0;j<16;++j){
    const int ci = 15 ^ MASK_OF[i], cj = 15 ^ MASK_OF[j];
    if((ci & cj) != 0) continue;
    const int mr = ci ^ cj, mk = 15 ^ mr;
    t.e[n].i=i; t.e[n].j=j; t.e[n].k=idx_of_mask(mk);
    t.e[n].s = dsign(MASK_OF[i]) * dsign(MASK_OF[j]) * rsign(ci,cj) * dsign(mk);
    ++n;
  }
  return t;
}
constexpr GPT GPt = make_gp();
constexpr JNT JNt = make_jn();
} // namespace ga

// ============================ helpers ============================
__device__ __forceinline__ float gelu_t(float x){
  const float u = 0.7978845608028654f * x * (1.0f + 0.044715f * x * x);
  return 0.5f * x * (1.0f + tanhf(u));
}
__device__ __forceinline__ int swz(int p, int byteoff){ return byteoff ^ ((p & 7) << 4); }
// HT half row address: 16B row per (p,o)
__device__ __forceinline__ int htaddr(int p, int o){ return (p << 11) + ((o * 16) ^ ((p & 7) << 4)); }

// ======================= prep: bcdm bf16 fragment weights =======================
__global__ void prep_bf(
    const float* __restrict__ gbo_w_mv, const float* __restrict__ gbo_w_s2mv,
    const float* __restrict__ gbo_w_mvs2s, const float* __restrict__ gbo_w_s2s,
    const float* __restrict__ l1_w_mv, const float* __restrict__ l1_w_s2mv,
    const float* __restrict__ l1_w_mvs2s, const float* __restrict__ l1_w_s2s,
    const float* __restrict__ l2_w_mv, const float* __restrict__ l2_w_s2mv,
    const float* __restrict__ l2_w_mvs2s, const float* __restrict__ l2_w_s2s,
    unsigned short* __restrict__ WBu)
{
  const int idx = blockIdx.x * 256 + threadIdx.x;
  if (idx >= TOT_BF) return;
  float v = 0.0f;
  if (idx < FB_S2MV_B) {
    const int st = idx / 36864, r2 = idx % 36864;
    const int k9 = r2 >> 12, r3 = r2 & 4095;
    const int nt = r3 >> 10, ks = (r3 >> 9) & 1, l = (r3 >> 3) & 63, e = r3 & 7;
    const int o = 16*nt + (l & 15), c = 32*ks + 8*(l >> 4) + e;
    const float* src = st==0 ? gbo_w_mv : (st==1 ? l1_w_mv : l2_w_mv);
    v = src[(o*64 + c)*9 + k9];
  } else if (idx < FB_S2S_B) {
    const float* src; int r, KS, KK;
    if (idx < FB_S2MV_C)      { r = idx - FB_S2MV_B; KS=4; KK=128; src=gbo_w_s2mv; }
    else if (idx < FB_S2MV_D) { r = idx - FB_S2MV_C; KS=8; KK=256; src=l1_w_s2mv; }
    else                      { r = idx - FB_S2MV_D; KS=8; KK=256; src=l2_w_s2mv; }
    const int per = KS*512, nt = r / per, r3 = r % per;
    const int ks = r3 >> 9, l = (r3 >> 3) & 63, e = r3 & 7;
    const int o = 16*nt + (l & 15), k = 32*ks + 8*(l >> 4) + e;
    v = src[o*KK + k];
  } else if (idx < FB_MS2S_B) {
    const float* src; int r, KS, KK;
    if (idx < FB_S2S_C)      { r = idx - FB_S2S_B; KS=4; KK=128; src=gbo_w_s2s; }
    else if (idx < FB_S2S_D) { r = idx - FB_S2S_C; KS=8; KK=256; src=l1_w_s2s; }
    else                     { r = idx - FB_S2S_D; KS=8; KK=256; src=l2_w_s2s; }
    const int per = KS*512, nt = r / per, r3 = r % per;
    const int ks = r3 >> 9, l = (r3 >> 3) & 63, e = r3 & 7;
    const int o = 16*nt + (l & 15), k = 32*ks + 8*(l >> 4) + e;
    v = src[o*KK + k];
  } else {
    const float* src; int r;
    if (idx < FB_MS2S_C)      { r = idx - FB_MS2S_B; src = gbo_w_mvs2s; }
    else if (idx < FB_MS2S_D) { r = idx - FB_MS2S_C; src = l1_w_mvs2s; }
    else                      { r = idx - FB_MS2S_D; src = l2_w_mvs2s; }
    const int nt = r >> 10, r3 = r & 1023;
    const int ks = r3 >> 9, l = (r3 >> 3) & 63, e = r3 & 7;
    const int o = 16*nt + (l & 15), k = 32*ks + 8*(l >> 4) + e;
    v = src[o*64 + k];
  }
  __bf16* WB = (__bf16*)WBu;
  const __bf16 h = (__bf16)v;
  WB[idx] = h;
  WB[TOT_BF + idx] = (__bf16)(v - (float)h);
}

// ======================= prep: stage-A bf16 fragments =======================
__global__ void prep_ga(const float* __restrict__ gb_w_mv,
                        const float* __restrict__ gb_w_s2mv,
                        unsigned short* __restrict__ WBu)
{
  const int idx = blockIdx.x * 256 + threadIdx.x;
  if (idx >= SA_TOT) return;
  float v;
  if (idx < GAS2_OFF) {                 // [9k][8nt][2ks][64l][8e]
    const int k9 = idx >> 13, r3 = idx & 8191;
    const int nt = r3 >> 10, ks = (r3 >> 9) & 1, l = (r3 >> 3) & 63, e = r3 & 7;
    const int o = 16*nt + (l & 15), c = 32*ks + 8*(l >> 4) + e;
    v = gb_w_mv[(o*64 + c)*9 + k9];
  } else {                              // [8nt][4ks][64l][8e]
    const int r = idx - GAS2_OFF;
    const int nt = r >> 11, ks = (r >> 9) & 3, l = (r >> 3) & 63, e = r & 7;
    const int o = 16*nt + (l & 15), k = 32*ks + 8*(l >> 4) + e;
    v = gb_w_s2mv[o*128 + k];
  }
  __bf16* WB = (__bf16*)WBu;
  const __bf16 h = (__bf16)v;
  WB[SAW + idx] = h;
  WB[SAW + SA_TOT + idx] = (__bf16)(v - (float)h);   // lo kept (unused)
}

// ======================= MFMA helpers =======================
template<int PASS>
__device__ __forceinline__ void ga_half(f32x4 (&acc)[8], const __bf16* __restrict__ WB,
                                        const unsigned char* lds, int nt, int lane)
{
  constexpr int GR[16] = {0,1,1,1,1,2,2,2,2,2,2,3,3,3,3,4};
  constexpr int PJ[16] = {-1,0,-1,-1,-1,2,3,4,-1,-1,-1,8,9,10,-1,14};
  constexpr int KE[16] = {0,5,0,0,0,6,6,6,0,0,0,7,7,7,0,8};
  const int pa  = lane & 15;
  const int cb0 = (lane >> 4) << 4;
  const int wl8 = lane << 3;
  #pragma unroll
  for (int jl = 0; jl < 8; ++jl) {
    const int j = PASS*8 + jl;
    #pragma unroll
    for (int ks = 0; ks < 2; ++ks) {
      bf16x8 a = *(const bf16x8*)(lds + XA_OFF + (((j<<4)+pa)<<7) + swz(pa, cb0 + (ks<<6)));
      const __bf16* bp = WB + SAW + GR[j]*8192 + (nt<<10) + (ks<<9) + wl8;
      acc[jl] = __builtin_amdgcn_mfma_f32_16x16x32_bf16(a, *(const bf16x8*)bp, acc[jl], 0, 0, 0);
    }
    if (PJ[j] >= 0) {
      #pragma unroll
      for (int ks = 0; ks < 2; ++ks) {
        bf16x8 a = *(const bf16x8*)(lds + XA_OFF + (((PJ[j]<<4)+pa)<<7) + swz(pa, cb0 + (ks<<6)));
        const __bf16* bp = WB + SAW + KE[j]*8192 + (nt<<10) + (ks<<9) + wl8;
        acc[jl] = __builtin_amdgcn_mfma_f32_16x16x32_bf16(a, *(const bf16x8*)bp, acc[jl], 0, 0, 0);
      }
    }
  }
}
template<int JH>
__device__ __forceinline__ void mv_half(f32x4 (&acc)[8], const __bf16* __restrict__ WB,
                                        const unsigned char* lds, int mvbase, int w, int lane)
{
  constexpr int GRa[2][8] = {{0,1,1,1,1,2,2,2},{2,2,2,3,3,3,3,4}};
  constexpr int PJa[2][8] = {{-1,0,-1,-1,-1,2,3,4},{-1,-1,-1,8,9,10,-1,14}};
  constexpr int KEa[2][8] = {{0,5,0,0,0,6,6,6},{0,0,0,7,7,7,0,8}};
  const int pa  = lane & 15;
  const int cb0 = (lane >> 4) << 4;
  const int wl8 = lane << 3;
  #pragma unroll
  for (int jl = 0; jl < 8; ++jl) {
    const int j = JH*8 + jl;
    #pragma unroll
    for (int ks = 0; ks < 2; ++ks) {
      bf16x8 a = *(const bf16x8*)(lds + XA_OFF + (((j<<4)+pa)<<7) + swz(pa, cb0 + (ks<<6)));
      const __bf16* bp = WB + mvbase + GRa[JH][jl]*4096 + (w<<10) + (ks<<9) + wl8;
      acc[jl] = __builtin_amdgcn_mfma_f32_16x16x32_bf16(a, *(const bf16x8*)bp, acc[jl], 0, 0, 0);
    }
    if (PJa[JH][jl] >= 0) {
      #pragma unroll
      for (int ks = 0; ks < 2; ++ks) {
        bf16x8 a = *(const bf16x8*)(lds + XA_OFF + (((PJa[JH][jl]<<4)+pa)<<7) + swz(pa, cb0 + (ks<<6)));
        const __bf16* bp = WB + mvbase + KEa[JH][jl]*4096 + (w<<10) + (ks<<9) + wl8;
        acc[jl] = __builtin_amdgcn_mfma_f32_16x16x32_bf16(a, *(const bf16x8*)bp, acc[jl], 0, 0, 0);
      }
    }
  }
}
template<int KS, int RSH>
__device__ __forceinline__ void s_gemm(f32x4& acc, const __bf16* __restrict__ WB,
                                       const unsigned char* lds, int abase, int wbase, int lane)
{
  const int pa  = lane & 15;
  const int cb0 = (lane >> 4) << 4;
  const int wl8 = lane << 3;
  #pragma unroll
  for (int ks = 0; ks < KS; ++ks) {
    bf16x8 a = *(const bf16x8*)(lds + abase + (pa << RSH) + swz(pa, cb0 + (ks << 6)));
    const __bf16* bp = WB + wbase + (ks << 9) + wl8;
    acc = __builtin_amdgcn_mfma_f32_16x16x32_bf16(a, *(const bf16x8*)bp, acc, 0, 0, 0);
  }
}

// ======================= fused_all: A + GP/JOIN + B/C/D =======================
// R19: GP/JOIN outputs packed to bf16x8 immediately (8 VGPR live across the
// barrier instead of 32 floats; peak live during JOIN 52 vs 64+) -- R16-R18's
// constant 250B/thread spill matches gpo+jno+L+R = 64 dwords.
__global__ __launch_bounds__(512, 1) void fused_all(
    const float* __restrict__ xin,  const float* __restrict__ sinp,
    const float* __restrict__ gb_b_mv,
    const float* __restrict__ gbo_b_mv, const float* __restrict__ gbo_b_s,
    const float* __restrict__ l1_b_mv,  const float* __restrict__ l1_b_s,
    const float* __restrict__ l2_b_mv,  const float* __restrict__ l2_b_s,
    const unsigned short* __restrict__ WBu,
    float* __restrict__ out)
{
  __shared__ __align__(16) unsigned char lds[LDS_BYTES];
  const __bf16* WB = (const __bf16*)WBu;
  const int tid = threadIdx.x, lane = tid & 63, wv = tid >> 6;
  const int pg = lane >> 4, ol = lane & 15;
  const int n0 = blockIdx.x * 16;

  // ---------------- stage xin -> XA, sinp -> SA ----------------
  {
    const float4* src = (const float4*)(xin + (size_t)n0 * 1024);
    #pragma unroll
    for (int q = 0; q < 8; ++q) {
      const int i = q * 512 + tid;
      const float4 v = src[i];
      const int p = i >> 8, c = (i >> 2) & 63, j0 = (i & 3) << 2;
      const float vv[4] = {v.x, v.y, v.z, v.w};
      #pragma unroll
      for (int t = 0; t < 4; ++t)
        *(__bf16*)(lds + XA_OFF + ((((j0 + t) << 4) + p) << 7) + swz(p, 2 * c)) = (__bf16)vv[t];
    }
    {
      const float4 v = ((const float4*)(sinp + (size_t)n0 * 128))[tid];
      const int p = tid >> 5, k0 = (tid & 31) << 2;
      const float vv[4] = {v.x, v.y, v.z, v.w};
      #pragma unroll
      for (int t = 0; t < 4; ++t)
        *(__bf16*)(lds + SA_OFF + (p << 8) + swz(p, 2 * (k0 + t))) = (__bf16)vv[t];
    }
  }
  __syncthreads();

  // ---------------- phase A GEMM: two 8-blade passes ----------------
  {
    const int nt = wv;
    const int o = 16*nt + ol;
    { // pass 0: blades 0..7 (+ s2mv + bias on j0) -> HT0
      f32x4 acc[8];
      #pragma unroll
      for (int j = 0; j < 8; ++j) acc[j] = f32x4{0.f,0.f,0.f,0.f};
      ga_half<0>(acc, WB, lds, nt, lane);
      {
        const int pa  = lane & 15;
        const int cb0 = (lane >> 4) << 4;
        const int wl8 = lane << 3;
        #pragma unroll
        for (int ks = 0; ks < 4; ++ks) {
          bf16x8 a = *(const bf16x8*)(lds + SA_OFF + (pa << 8) + swz(pa, cb0 + (ks << 6)));
          const __bf16* bp = WB + SAW + GAS2_OFF + (nt<<11) + (ks<<9) + wl8;
          acc[0] = __builtin_amdgcn_mfma_f32_16x16x32_bf16(a, *(const bf16x8*)bp, acc[0], 0, 0, 0);
        }
        const float bm = gb_b_mv[o];
        #pragma unroll
        for (int r = 0; r < 4; ++r) acc[0][r] += bm;
      }
      #pragma unroll
      for (int r = 0; r < 4; ++r) {
        const int p = pg*4 + r;
        bf16x8 h0;
        #pragma unroll
        for (int j = 0; j < 8; ++j) h0[j] = (__bf16)acc[j][r];
        *(bf16x8*)(lds + HT0_OFF + htaddr(p, o)) = h0;
      }
    }
    { // pass 1: blades 8..15 -> HT1 (overlays XA; barrier first)
      f32x4 acc[8];
      #pragma unroll
      for (int j = 0; j < 8; ++j) acc[j] = f32x4{0.f,0.f,0.f,0.f};
      ga_half<1>(acc, WB, lds, nt, lane);
      __syncthreads();                 // all XA reads complete
      #pragma unroll
      for (int r = 0; r < 4; ++r) {
        const int p = pg*4 + r;
        bf16x8 h1;
        #pragma unroll
        for (int j = 0; j < 8; ++j) h1[j] = (__bf16)acc[j][r];
        *(bf16x8*)(lds + htaddr(p, o)) = h1;
      }
    }
  }
  __syncthreads();

  // ---------------- GP + JOIN, packed to bf16 immediately ----------------
  bf16x8 gph[2], jnh[2];
  {
    const int p2 = tid >> 5, ch = tid & 31;
    float L[16], R[16], o16[16];
    auto ldrow = [&](int row, float* X){
      bf16x8 a = *(const bf16x8*)(lds + HT0_OFF + htaddr(p2, row));
      bf16x8 b = *(const bf16x8*)(lds + htaddr(p2, row));
      #pragma unroll
      for (int t = 0; t < 8; ++t) { X[t] = (float)a[t]; X[8+t] = (float)b[t]; }
    };
    ldrow(ch, L); ldrow(32 + ch, R);
    #pragma unroll
    for (int j = 0; j < 16; ++j) o16[j] = 0.0f;
    #pragma unroll
    for (int n = 0; n < 192; ++n)
      o16[ga::GPt.e[n].k] = fmaf(ga::GPt.e[n].s * L[ga::GPt.e[n].i], R[ga::GPt.e[n].j], o16[ga::GPt.e[n].k]);
    #pragma unroll
    for (int t = 0; t < 8; ++t) { gph[0][t] = (__bf16)o16[t]; gph[1][t] = (__bf16)o16[8+t]; }
    ldrow(64 + ch, L); ldrow(96 + ch, R);
    #pragma unroll
    for (int j = 0; j < 16; ++j) o16[j] = 0.0f;
    #pragma unroll
    for (int n = 0; n < 81; ++n)
      o16[ga::JNt.e[n].k] = fmaf(ga::JNt.e[n].s * L[ga::JNt.e[n].i], R[ga::JNt.e[n].j], o16[ga::JNt.e[n].k]);
    #pragma unroll
    for (int t = 0; t < 8; ++t) { jnh[0][t] = (__bf16)o16[t]; jnh[1][t] = (__bf16)o16[8+t]; }
  }
  __syncthreads();                     // HT reads complete -> overlay XA/C0

  { // write hidden -> XA bf16 [16j][16p][64c] + C0
    const int p2 = tid >> 5, ch = tid & 31;
    #pragma unroll
    for (int j = 0; j < 16; ++j) {
      const __bf16 gv = (j < 8) ? gph[0][j & 7] : gph[1][j & 7];
      const __bf16 jv = (j < 8) ? jnh[0][j & 7] : jnh[1][j & 7];
      *(__bf16*)(lds + XA_OFF + (((j<<4)+p2)<<7) + swz(p2, 2*ch))      = gv;
      *(__bf16*)(lds + XA_OFF + (((j<<4)+p2)<<7) + swz(p2, 2*(32+ch))) = jv;
    }
    *(__bf16*)(lds + C0_OFF + (p2<<7) + swz(p2, 2*ch))      = gph[0][0];
    *(__bf16*)(lds + C0_OFF + (p2<<7) + swz(p2, 2*(32+ch))) = jnh[0][0];
  }
  __syncthreads();

  // ---------------- phases B, C, D (hi-only) ----------------
  const int w = wv & 3, jh = wv >> 2;
  float* REDEQ = (float*)(lds + RED_OFF);        // [8][16]
  float* REDS  = REDEQ + 128;
  float* REDQ  = REDEQ + 256;
  float* GT    = (float*)(lds + GT_OFF);         // [16p][64o]

  #pragma unroll 1
  for (int stage = 0; stage < 2; ++stage) {
    const int mvb   = stage == 0 ? FB_MVB    : FB_MVC;
    const int s2mvb = stage == 0 ? FB_S2MV_B : FB_S2MV_C;
    const int s2sb  = stage == 0 ? FB_S2S_B  : FB_S2S_C;
    const int ms2sb = stage == 0 ? FB_MS2S_B : FB_MS2S_C;
    const int sab   = stage == 0 ? SA_OFF    : T1_OFF;
    const int tdst  = stage == 0 ? T1_OFF    : T2_OFF;
    const float* b_mv = stage == 0 ? gbo_b_mv : l1_b_mv;
    const float* b_s  = stage == 0 ? gbo_b_s  : l1_b_s;
    const int nt0 = 4*w + 2*jh;

    f32x4 acc[8], fac[2];
    #pragma unroll
    for (int j = 0; j < 8; ++j) acc[j] = f32x4{0.f,0.f,0.f,0.f};
    fac[0] = f32x4{0.f,0.f,0.f,0.f}; fac[1] = f32x4{0.f,0.f,0.f,0.f};

    if (jh == 0) mv_half<0>(acc, WB, lds, mvb, w, lane);
    else         mv_half<1>(acc, WB, lds, mvb, w, lane);

    if (stage == 0) {
      if (jh == 0) s_gemm<4,8>(acc[0], WB, lds, sab, s2mvb + w*2048, lane);
      #pragma unroll
      for (int i = 0; i < 2; ++i) {
        s_gemm<4,8>(fac[i], WB, lds, sab, s2sb + (nt0+i)*2048, lane);
        s_gemm<2,7>(fac[i], WB, lds, C0_OFF, ms2sb + (nt0+i)*1024, lane);
      }
    } else {
      if (jh == 0) s_gemm<8,9>(acc[0], WB, lds, sab, s2mvb + w*4096, lane);
      #pragma unroll
      for (int i = 0; i < 2; ++i) {
        s_gemm<8,9>(fac[i], WB, lds, sab, s2sb + (nt0+i)*4096, lane);
        s_gemm<2,7>(fac[i], WB, lds, C0_OFF, ms2sb + (nt0+i)*1024, lane);
      }
    }
    __syncthreads();

    if (jh == 0) {
      const float bm = b_mv[16*w + ol];
      #pragma unroll
      for (int r = 0; r < 4; ++r) acc[0][r] += bm;
    }
    #pragma unroll
    for (int i = 0; i < 2; ++i) {
      const float bs = b_s[16*(nt0+i) + ol];
      #pragma unroll
      for (int r = 0; r < 4; ++r) fac[i][r] += bs;
    }
    float sq[4], sm[4], s2[4];
    #pragma unroll
    for (int r = 0; r < 4; ++r) {
      sq[r] = (jh == 0)
        ? acc[0][r]*acc[0][r] + acc[2][r]*acc[2][r] + acc[3][r]*acc[3][r] + acc[4][r]*acc[4][r]
        : acc[0][r]*acc[0][r] + acc[1][r]*acc[1][r] + acc[2][r]*acc[2][r] + acc[6][r]*acc[6][r];
      sm[r] = fac[0][r] + fac[1][r];
      s2[r] = fac[0][r]*fac[0][r] + fac[1][r]*fac[1][r];
    }
    #pragma unroll
    for (int m = 1; m < 16; m <<= 1) {
      #pragma unroll
      for (int r = 0; r < 4; ++r) {
        sq[r] += __shfl_xor(sq[r], m);
        sm[r] += __shfl_xor(sm[r], m);
        s2[r] += __shfl_xor(s2[r], m);
      }
    }
    if (ol == 0) {
      #pragma unroll
      for (int r = 0; r < 4; ++r) {
        const int p = pg*4 + r;
        REDEQ[wv*16 + p] = sq[r]; REDS[wv*16 + p] = sm[r]; REDQ[wv*16 + p] = s2[r];
      }
    }
    __syncthreads();

    float rs[4], mu[4], rstd[4];
    #pragma unroll
    for (int r = 0; r < 4; ++r) {
      const int p = pg*4 + r;
      float te = 0.f, ts = 0.f, tq = 0.f;
      #pragma unroll
      for (int v2 = 0; v2 < 8; ++v2) { te += REDEQ[v2*16+p]; ts += REDS[v2*16+p]; tq += REDQ[v2*16+p]; }
      rs[r]   = 1.0f / sqrtf(fmaxf(te * (1.0f/64.0f), 0.01f));
      mu[r]   = ts * (1.0f/256.0f);
      rstd[r] = rsqrtf(tq * (1.0f/256.0f) - mu[r]*mu[r] + 1e-5f);
    }
    #pragma unroll
    for (int i = 0; i < 2; ++i) {
      #pragma unroll
      for (int r = 0; r < 4; ++r) {
        const int p = pg*4 + r, op = 16*(nt0+i) + ol;
        *(__bf16*)(lds + tdst + (p << 9) + swz(p, 2*op)) =
            (__bf16)gelu_t((fac[i][r] - mu[r]) * rstd[r]);
      }
    }
    if (jh == 0) {
      const int cnew = 16*w + ol;
      #pragma unroll
      for (int r = 0; r < 4; ++r) {
        const int p = pg*4 + r;
        const float a0n = acc[0][r] * rs[r];
        const float g   = gelu_t(a0n);
        GT[p*64 + cnew] = g;
        *(__bf16*)(lds + C0_OFF + (p<<7) + swz(p, 2*cnew)) = (__bf16)(g * a0n);
      }
    }
    __syncthreads();

    {
      const int cnew = 16*w + ol;
      float f[4];
      #pragma unroll
      for (int r = 0; r < 4; ++r) f[r] = rs[r] * GT[(pg*4+r)*64 + cnew];
      #pragma unroll
      for (int jl = 0; jl < 8; ++jl) {
        const int j = jh*8 + jl;
        #pragma unroll
        for (int r = 0; r < 4; ++r) {
          const int p = pg*4 + r;
          *(__bf16*)(lds + XA_OFF + (((j<<4)+p)<<7) + swz(p, 2*cnew)) = (__bf16)(acc[jl][r] * f[r]);
        }
      }
    }
    __syncthreads();
  }

  { // ---------------- stage D ----------------
    f32x4 acc[8], fac2;
    #pragma unroll
    for (int j = 0; j < 8; ++j) acc[j] = f32x4{0.f,0.f,0.f,0.f};
    fac2 = f32x4{0.f,0.f,0.f,0.f};

    if (jh == 0) mv_half<0>(acc, WB, lds, FB_MVD, w, lane);
    else         mv_half<1>(acc, WB, lds, FB_MVD, w, lane);
    if (jh == 0) s_gemm<8,9>(acc[0], WB, lds, T2_OFF, FB_S2MV_D + w*4096, lane);
    const int ntd = w + 4*jh;
    s_gemm<8,9>(fac2, WB, lds, T2_OFF, FB_S2S_D + ntd*4096, lane);
    s_gemm<2,7>(fac2, WB, lds, C0_OFF, FB_MS2S_D + ntd*1024, lane);

    if (jh == 0) {
      const float bm = l2_b_mv[16*w + ol];
      #pragma unroll
      for (int r = 0; r < 4; ++r) acc[0][r] += bm;
    }
    #pragma unroll
    for (int r = 0; r < 4; ++r) {
      const int p = pg*4 + r;
      float* dst = out + ((size_t)(n0 + p)*64 + 16*w + ol)*16 + jh*8;
      *(float4*)(dst+0) = make_float4(acc[0][r], acc[1][r], acc[2][r], acc[3][r]);
      *(float4*)(dst+4) = make_float4(acc[4][r], acc[5][r], acc[6][r], acc[7][r]);
    }
    {
      const int od = 16*ntd + ol;
      const float bs = l2_b_s[od];
      #pragma unroll
      for (int r = 0; r < 4; ++r) {
        const int p = pg*4 + r;
        out[SOFF + (size_t)(n0 + p)*128 + od] = fac2[r] + bs;
      }
    }
  }
}

// ============================ host launch ============================
extern "C" void kernel_launch(void* const* d_in, const int* in_sizes, int n_in,
                              void* d_out, int out_size, void* d_ws, size_t ws_size,
                              hipStream_t stream) {
  const float* xin          = (const float*)d_in[0];
  const float* sinp         = (const float*)d_in[1];
  const float* gb_w_mv      = (const float*)d_in[2];
  const float* gb_w_s2mv    = (const float*)d_in[3];
  const float* gb_b_mv      = (const float*)d_in[4];
  const float* gbo_w_mv     = (const float*)d_in[5];
  const float* gbo_w_s2mv   = (const float*)d_in[6];
  const float* gbo_b_mv     = (const float*)d_in[7];
  const float* gbo_w_mvs2s  = (const float*)d_in[8];
  const float* gbo_w_s2s    = (const float*)d_in[9];
  const float* gbo_b_s      = (const float*)d_in[10];
  const float* l1_w_mv      = (const float*)d_in[11];
  const float* l1_w_s2mv    = (const float*)d_in[12];
  const float* l1_b_mv      = (const float*)d_in[13];
  const float* l1_w_mvs2s   = (const float*)d_in[14];
  const float* l1_w_s2s     = (const float*)d_in[15];
  const float* l1_b_s       = (const float*)d_in[16];
  const float* l2_w_mv      = (const float*)d_in[17];
  const float* l2_w_s2mv    = (const float*)d_in[18];
  const float* l2_b_mv      = (const float*)d_in[19];
  const float* l2_w_mvs2s   = (const float*)d_in[20];
  const float* l2_w_s2s     = (const float*)d_in[21];
  const float* l2_b_s       = (const float*)d_in[22];
  unsigned short* WBu = (unsigned short*)d_ws;
  float* out = (float*)d_out;

  prep_bf<<<(TOT_BF + 255) / 256, 256, 0, stream>>>(
      gbo_w_mv, gbo_w_s2mv, gbo_w_mvs2s, gbo_w_s2s,
      l1_w_mv, l1_w_s2mv, l1_w_mvs2s, l1_w_s2s,
      l2_w_mv, l2_w_s2mv, l2_w_mvs2s, l2_w_s2s, WBu);

  prep_ga<<<(SA_TOT + 255) / 256, 256, 0, stream>>>(gb_w_mv, gb_w_s2mv, WBu);

  fused_all<<<NPTS / 16, 512, 0, stream>>>(
      xin, sinp, gb_b_mv, gbo_b_mv, gbo_b_s, l1_b_mv, l1_b_s,
      l2_b_mv, l2_b_s, WBu, out);
}

// Round 20
// 378.669 us; speedup vs baseline: 1.0002x; 1.0002x over previous
//
#include <hip/hip_runtime.h>
#include <math.h>

typedef __bf16 bf16x8 __attribute__((ext_vector_type(8)));
typedef float  f32x4  __attribute__((ext_vector_type(4)));

// ============================ constants ============================
constexpr int NPTS = 32768;
constexpr long long SOFF = 33554432LL;        // NPTS*64*16, start of scalar outputs

// ---- bf16 fragment region (all weights), element offsets in WBu ----
constexpr int TOT_BF   = 323584;
constexpr int FB_MVB    = 0;
constexpr int FB_MVC    = 36864;
constexpr int FB_MVD    = 73728;
constexpr int FB_S2MV_B = 110592;
constexpr int FB_S2MV_C = 118784;
constexpr int FB_S2MV_D = 135168;
constexpr int FB_S2S_B  = 151552;
constexpr int FB_S2S_C  = 184320;
constexpr int FB_S2S_D  = 249856;
constexpr int FB_MS2S_B = 282624;
constexpr int FB_MS2S_C = 299008;
constexpr int FB_MS2S_D = 315392;
// stage-A frags: hi at [SAW, SAW+SA_TOT), lo at [SAW+SA_TOT, SAW+2*SA_TOT)
constexpr int SAW      = 647168;
constexpr int GAS2_OFF = 73728;
constexpr int SA_TOT   = 90112;

// ---- fused LDS layout (bytes) ----
constexpr int XA_OFF  = 0;        // bf16 [16j][16p][64c] swizzled, 32768
constexpr int HT0_OFF = 32768;    // bf16 [16p][128 rows][8j(0-7)] 16B rows, 32768
// HT1 (j8-15) overlays XA at [0,32768) after phase-A reads complete
// stage-D exchange buffer (f32 [16p][64o][8j]) also overlays XA after D-GEMMs
constexpr int T1_OFF  = 36864;    // bf16 [16p][256] swizzled, 8192
constexpr int T2_OFF  = 45056;    // 8192
constexpr int C0_OFF  = 53248;    // bf16 [16p][64] swizzled, 2048
constexpr int GT_OFF  = 55296;    // f32 [16p][64o] gate, 4096
constexpr int RED_OFF = 59392;    // 3 x f32[8wv][16p] = 1536 (ends 60928)
constexpr int SA_OFF  = 65536;    // bf16 [16p][128] swizzled, 4096
constexpr int LDS_BYTES = 69632;  // 2 blocks/CU

// ==================== compile-time GA tables (GP/JOIN) ====================
namespace ga {
constexpr int MASK_OF[16] = {0,1,2,4,8,3,5,9,6,10,12,7,11,13,14,15};
constexpr int idx_of_mask(int m){ int r = 0; for(int i=0;i<16;++i) if(MASK_OF[i]==m) r=i; return r; }
constexpr int pcount(int x){ int c=0; while(x){ c += x&1; x >>= 1; } return c; }
constexpr int nswaps(int a,int b){ int s=0; a >>= 1; while(a){ s += pcount(a&b); a >>= 1; } return s; }
constexpr float rsign(int a,int b){ return (nswaps(a,b)&1) ? -1.0f : 1.0f; }
constexpr float dsign(int m){ return rsign(m, 15^m); }
struct Ent { int i, j, k; float s; };
struct GPT { Ent e[192]; };
constexpr GPT make_gp(){
  GPT t{}; int n=0;
  for(int i=0;i<16;++i) for(int j=0;j<16;++j){
    const int a=MASK_OF[i], b=MASK_OF[j];
    if((a & b & 1) != 0) continue;
    t.e[n].i=i; t.e[n].j=j; t.e[n].k=idx_of_mask(a^b); t.e[n].s=rsign(a,b); ++n;
  }
  return t;
}
struct JNT { Ent e[81]; };
constexpr JNT make_jn(){
  JNT t{}; int n=0;
  for(int i=0;i<16;++i) for(int j=0;j<16;++j){
    const int ci = 15 ^ MASK_OF[i], cj = 15 ^ MASK_OF[j];
    if((ci & cj) != 0) continue;
    const int mr = ci ^ cj, mk = 15 ^ mr;
    t.e[n].i=i; t.e[n].j=j; t.e[n].k=idx_of_mask(mk);
    t.e[n].s = dsign(MASK_OF[i]) * dsign(MASK_OF[j]) * rsign(ci,cj) * dsign(mk);
    ++n;
  }
  return t;
}
constexpr GPT GPt = make_gp();
constexpr JNT JNt = make_jn();
} // namespace ga

// ============================ helpers ============================
__device__ __forceinline__ float gelu_t(float x){
  const float u = 0.7978845608028654f * x * (1.0f + 0.044715f * x * x);
  return 0.5f * x * (1.0f + tanhf(u));
}
__device__ __forceinline__ int swz(int p, int byteoff){ return byteoff ^ ((p & 7) << 4); }
__device__ __forceinline__ int htaddr(int p, int o){ return (p << 11) + ((o * 16) ^ ((p & 7) << 4)); }

// ======================= prep: bcdm bf16 fragment weights =======================
__global__ void prep_bf(
    const float* __restrict__ gbo_w_mv, const float* __restrict__ gbo_w_s2mv,
    const float* __restrict__ gbo_w_mvs2s, const float* __restrict__ gbo_w_s2s,
    const float* __restrict__ l1_w_mv, const float* __restrict__ l1_w_s2mv,
    const float* __restrict__ l1_w_mvs2s, const float* __restrict__ l1_w_s2s,
    const float* __restrict__ l2_w_mv, const float* __restrict__ l2_w_s2mv,
    const float* __restrict__ l2_w_mvs2s, const float* __restrict__ l2_w_s2s,
    unsigned short* __restrict__ WBu)
{
  const int idx = blockIdx.x * 256 + threadIdx.x;
  if (idx >= TOT_BF) return;
  float v = 0.0f;
  if (idx < FB_S2MV_B) {
    const int st = idx / 36864, r2 = idx % 36864;
    const int k9 = r2 >> 12, r3 = r2 & 4095;
    const int nt = r3 >> 10, ks = (r3 >> 9) & 1, l = (r3 >> 3) & 63, e = r3 & 7;
    const int o = 16*nt + (l & 15), c = 32*ks + 8*(l >> 4) + e;
    const float* src = st==0 ? gbo_w_mv : (st==1 ? l1_w_mv : l2_w_mv);
    v = src[(o*64 + c)*9 + k9];
  } else if (idx < FB_S2S_B) {
    const float* src; int r, KS, KK;
    if (idx < FB_S2MV_C)      { r = idx - FB_S2MV_B; KS=4; KK=128; src=gbo_w_s2mv; }
    else if (idx < FB_S2MV_D) { r = idx - FB_S2MV_C; KS=8; KK=256; src=l1_w_s2mv; }
    else                      { r = idx - FB_S2MV_D; KS=8; KK=256; src=l2_w_s2mv; }
    const int per = KS*512, nt = r / per, r3 = r % per;
    const int ks = r3 >> 9, l = (r3 >> 3) & 63, e = r3 & 7;
    const int o = 16*nt + (l & 15), k = 32*ks + 8*(l >> 4) + e;
    v = src[o*KK + k];
  } else if (idx < FB_MS2S_B) {
    const float* src; int r, KS, KK;
    if (idx < FB_S2S_C)      { r = idx - FB_S2S_B; KS=4; KK=128; src=gbo_w_s2s; }
    else if (idx < FB_S2S_D) { r = idx - FB_S2S_C; KS=8; KK=256; src=l1_w_s2s; }
    else                     { r = idx - FB_S2S_D; KS=8; KK=256; src=l2_w_s2s; }
    const int per = KS*512, nt = r / per, r3 = r % per;
    const int ks = r3 >> 9, l = (r3 >> 3) & 63, e = r3 & 7;
    const int o = 16*nt + (l & 15), k = 32*ks + 8*(l >> 4) + e;
    v = src[o*KK + k];
  } else {
    const float* src; int r;
    if (idx < FB_MS2S_C)      { r = idx - FB_MS2S_B; src = gbo_w_mvs2s; }
    else if (idx < FB_MS2S_D) { r = idx - FB_MS2S_C; src = l1_w_mvs2s; }
    else                      { r = idx - FB_MS2S_D; src = l2_w_mvs2s; }
    const int nt = r >> 10, r3 = r & 1023;
    const int ks = r3 >> 9, l = (r3 >> 3) & 63, e = r3 & 7;
    const int o = 16*nt + (l & 15), k = 32*ks + 8*(l >> 4) + e;
    v = src[o*64 + k];
  }
  __bf16* WB = (__bf16*)WBu;
  const __bf16 h = (__bf16)v;
  WB[idx] = h;
  WB[TOT_BF + idx] = (__bf16)(v - (float)h);
}

// ======================= prep: stage-A bf16 fragments =======================
__global__ void prep_ga(const float* __restrict__ gb_w_mv,
                        const float* __restrict__ gb_w_s2mv,
                        unsigned short* __restrict__ WBu)
{
  const int idx = blockIdx.x * 256 + threadIdx.x;
  if (idx >= SA_TOT) return;
  float v;
  if (idx < GAS2_OFF) {                 // [9k][8nt][2ks][64l][8e]
    const int k9 = idx >> 13, r3 = idx & 8191;
    const int nt = r3 >> 10, ks = (r3 >> 9) & 1, l = (r3 >> 3) & 63, e = r3 & 7;
    const int o = 16*nt + (l & 15), c = 32*ks + 8*(l >> 4) + e;
    v = gb_w_mv[(o*64 + c)*9 + k9];
  } else {                              // [8nt][4ks][64l][8e]
    const int r = idx - GAS2_OFF;
    const int nt = r >> 11, ks = (r >> 9) & 3, l = (r >> 3) & 63, e = r & 7;
    const int o = 16*nt + (l & 15), k = 32*ks + 8*(l >> 4) + e;
    v = gb_w_s2mv[o*128 + k];
  }
  __bf16* WB = (__bf16*)WBu;
  const __bf16 h = (__bf16)v;
  WB[SAW + idx] = h;
  WB[SAW + SA_TOT + idx] = (__bf16)(v - (float)h);   // lo kept (unused)
}

// ======================= MFMA helpers =======================
template<int PASS>
__device__ __forceinline__ void ga_half(f32x4 (&acc)[8], const __bf16* __restrict__ WB,
                                        const unsigned char* lds, int nt, int lane)
{
  constexpr int GR[16] = {0,1,1,1,1,2,2,2,2,2,2,3,3,3,3,4};
  constexpr int PJ[16] = {-1,0,-1,-1,-1,2,3,4,-1,-1,-1,8,9,10,-1,14};
  constexpr int KE[16] = {0,5,0,0,0,6,6,6,0,0,0,7,7,7,0,8};
  const int pa  = lane & 15;
  const int cb0 = (lane >> 4) << 4;
  const int wl8 = lane << 3;
  #pragma unroll
  for (int jl = 0; jl < 8; ++jl) {
    const int j = PASS*8 + jl;
    #pragma unroll
    for (int ks = 0; ks < 2; ++ks) {
      bf16x8 a = *(const bf16x8*)(lds + XA_OFF + (((j<<4)+pa)<<7) + swz(pa, cb0 + (ks<<6)));
      const __bf16* bp = WB + SAW + GR[j]*8192 + (nt<<10) + (ks<<9) + wl8;
      acc[jl] = __builtin_amdgcn_mfma_f32_16x16x32_bf16(a, *(const bf16x8*)bp, acc[jl], 0, 0, 0);
    }
    if (PJ[j] >= 0) {
      #pragma unroll
      for (int ks = 0; ks < 2; ++ks) {
        bf16x8 a = *(const bf16x8*)(lds + XA_OFF + (((PJ[j]<<4)+pa)<<7) + swz(pa, cb0 + (ks<<6)));
        const __bf16* bp = WB + SAW + KE[j]*8192 + (nt<<10) + (ks<<9) + wl8;
        acc[jl] = __builtin_amdgcn_mfma_f32_16x16x32_bf16(a, *(const bf16x8*)bp, acc[jl], 0, 0, 0);
      }
    }
  }
}
template<int JH>
__device__ __forceinline__ void mv_half(f32x4 (&acc)[8], const __bf16* __restrict__ WB,
                                        const unsigned char* lds, int mvbase, int w, int lane)
{
  constexpr int GRa[2][8] = {{0,1,1,1,1,2,2,2},{2,2,2,3,3,3,3,4}};
  constexpr int PJa[2][8] = {{-1,0,-1,-1,-1,2,3,4},{-1,-1,-1,8,9,10,-1,14}};
  constexpr int KEa[2][8] = {{0,5,0,0,0,6,6,6},{0,0,0,7,7,7,0,8}};
  const int pa  = lane & 15;
  const int cb0 = (lane >> 4) << 4;
  const int wl8 = lane << 3;
  #pragma unroll
  for (int jl = 0; jl < 8; ++jl) {
    const int j = JH*8 + jl;
    #pragma unroll
    for (int ks = 0; ks < 2; ++ks) {
      bf16x8 a = *(const bf16x8*)(lds + XA_OFF + (((j<<4)+pa)<<7) + swz(pa, cb0 + (ks<<6)));
      const __bf16* bp = WB + mvbase + GRa[JH][jl]*4096 + (w<<10) + (ks<<9) + wl8;
      acc[jl] = __builtin_amdgcn_mfma_f32_16x16x32_bf16(a, *(const bf16x8*)bp, acc[jl], 0, 0, 0);
    }
    if (PJa[JH][jl] >= 0) {
      #pragma unroll
      for (int ks = 0; ks < 2; ++ks) {
        bf16x8 a = *(const bf16x8*)(lds + XA_OFF + (((PJa[JH][jl]<<4)+pa)<<7) + swz(pa, cb0 + (ks<<6)));
        const __bf16* bp = WB + mvbase + KEa[JH][jl]*4096 + (w<<10) + (ks<<9) + wl8;
        acc[jl] = __builtin_amdgcn_mfma_f32_16x16x32_bf16(a, *(const bf16x8*)bp, acc[jl], 0, 0, 0);
      }
    }
  }
}
template<int KS, int RSH>
__device__ __forceinline__ void s_gemm(f32x4& acc, const __bf16* __restrict__ WB,
                                       const unsigned char* lds, int abase, int wbase, int lane)
{
  const int pa  = lane & 15;
  const int cb0 = (lane >> 4) << 4;
  const int wl8 = lane << 3;
  #pragma unroll
  for (int ks = 0; ks < KS; ++ks) {
    bf16x8 a = *(const bf16x8*)(lds + abase + (pa << RSH) + swz(pa, cb0 + (ks << 6)));
    const __bf16* bp = WB + wbase + (ks << 9) + wl8;
    acc = __builtin_amdgcn_mfma_f32_16x16x32_bf16(a, *(const bf16x8*)bp, acc, 0, 0, 0);
  }
}

// ======================= fused_all: A + GP/JOIN + B/C/D =======================
// R20: (1) stage-D mv output assembled to FULL 64B lines via LDS exchange
// (R16-R19's constant 401MB WRITE = 2x write amplification from jh-split
// half-line stores). (2) B/C acc packed to bf16 before norm barriers (16 regs
// across barriers instead of 32).
__global__ __launch_bounds__(512, 1) void fused_all(
    const float* __restrict__ xin,  const float* __restrict__ sinp,
    const float* __restrict__ gb_b_mv,
    const float* __restrict__ gbo_b_mv, const float* __restrict__ gbo_b_s,
    const float* __restrict__ l1_b_mv,  const float* __restrict__ l1_b_s,
    const float* __restrict__ l2_b_mv,  const float* __restrict__ l2_b_s,
    const unsigned short* __restrict__ WBu,
    float* __restrict__ out)
{
  __shared__ __align__(16) unsigned char lds[LDS_BYTES];
  const __bf16* WB = (const __bf16*)WBu;
  const int tid = threadIdx.x, lane = tid & 63, wv = tid >> 6;
  const int pg = lane >> 4, ol = lane & 15;
  const int n0 = blockIdx.x * 16;

  // ---------------- stage xin -> XA, sinp -> SA ----------------
  {
    const float4* src = (const float4*)(xin + (size_t)n0 * 1024);
    #pragma unroll
    for (int q = 0; q < 8; ++q) {
      const int i = q * 512 + tid;
      const float4 v = src[i];
      const int p = i >> 8, c = (i >> 2) & 63, j0 = (i & 3) << 2;
      const float vv[4] = {v.x, v.y, v.z, v.w};
      #pragma unroll
      for (int t = 0; t < 4; ++t)
        *(__bf16*)(lds + XA_OFF + ((((j0 + t) << 4) + p) << 7) + swz(p, 2 * c)) = (__bf16)vv[t];
    }
    {
      const float4 v = ((const float4*)(sinp + (size_t)n0 * 128))[tid];
      const int p = tid >> 5, k0 = (tid & 31) << 2;
      const float vv[4] = {v.x, v.y, v.z, v.w};
      #pragma unroll
      for (int t = 0; t < 4; ++t)
        *(__bf16*)(lds + SA_OFF + (p << 8) + swz(p, 2 * (k0 + t))) = (__bf16)vv[t];
    }
  }
  __syncthreads();

  // ---------------- phase A GEMM: two 8-blade passes ----------------
  {
    const int nt = wv;
    const int o = 16*nt + ol;
    { // pass 0: blades 0..7 (+ s2mv + bias on j0) -> HT0
      f32x4 acc[8];
      #pragma unroll
      for (int j = 0; j < 8; ++j) acc[j] = f32x4{0.f,0.f,0.f,0.f};
      ga_half<0>(acc, WB, lds, nt, lane);
      {
        const int pa  = lane & 15;
        const int cb0 = (lane >> 4) << 4;
        const int wl8 = lane << 3;
        #pragma unroll
        for (int ks = 0; ks < 4; ++ks) {
          bf16x8 a = *(const bf16x8*)(lds + SA_OFF + (pa << 8) + swz(pa, cb0 + (ks << 6)));
          const __bf16* bp = WB + SAW + GAS2_OFF + (nt<<11) + (ks<<9) + wl8;
          acc[0] = __builtin_amdgcn_mfma_f32_16x16x32_bf16(a, *(const bf16x8*)bp, acc[0], 0, 0, 0);
        }
        const float bm = gb_b_mv[o];
        #pragma unroll
        for (int r = 0; r < 4; ++r) acc[0][r] += bm;
      }
      #pragma unroll
      for (int r = 0; r < 4; ++r) {
        const int p = pg*4 + r;
        bf16x8 h0;
        #pragma unroll
        for (int j = 0; j < 8; ++j) h0[j] = (__bf16)acc[j][r];
        *(bf16x8*)(lds + HT0_OFF + htaddr(p, o)) = h0;
      }
    }
    { // pass 1: blades 8..15 -> HT1 (overlays XA; barrier first)
      f32x4 acc[8];
      #pragma unroll
      for (int j = 0; j < 8; ++j) acc[j] = f32x4{0.f,0.f,0.f,0.f};
      ga_half<1>(acc, WB, lds, nt, lane);
      __syncthreads();                 // all XA reads complete
      #pragma unroll
      for (int r = 0; r < 4; ++r) {
        const int p = pg*4 + r;
        bf16x8 h1;
        #pragma unroll
        for (int j = 0; j < 8; ++j) h1[j] = (__bf16)acc[j][r];
        *(bf16x8*)(lds + htaddr(p, o)) = h1;
      }
    }
  }
  __syncthreads();

  // ---------------- GP + JOIN, packed to bf16 immediately ----------------
  bf16x8 gph[2], jnh[2];
  {
    const int p2 = tid >> 5, ch = tid & 31;
    float L[16], R[16], o16[16];
    auto ldrow = [&](int row, float* X){
      bf16x8 a = *(const bf16x8*)(lds + HT0_OFF + htaddr(p2, row));
      bf16x8 b = *(const bf16x8*)(lds + htaddr(p2, row));
      #pragma unroll
      for (int t = 0; t < 8; ++t) { X[t] = (float)a[t]; X[8+t] = (float)b[t]; }
    };
    ldrow(ch, L); ldrow(32 + ch, R);
    #pragma unroll
    for (int j = 0; j < 16; ++j) o16[j] = 0.0f;
    #pragma unroll
    for (int n = 0; n < 192; ++n)
      o16[ga::GPt.e[n].k] = fmaf(ga::GPt.e[n].s * L[ga::GPt.e[n].i], R[ga::GPt.e[n].j], o16[ga::GPt.e[n].k]);
    #pragma unroll
    for (int t = 0; t < 8; ++t) { gph[0][t] = (__bf16)o16[t]; gph[1][t] = (__bf16)o16[8+t]; }
    ldrow(64 + ch, L); ldrow(96 + ch, R);
    #pragma unroll
    for (int j = 0; j < 16; ++j) o16[j] = 0.0f;
    #pragma unroll
    for (int n = 0; n < 81; ++n)
      o16[ga::JNt.e[n].k] = fmaf(ga::JNt.e[n].s * L[ga::JNt.e[n].i], R[ga::JNt.e[n].j], o16[ga::JNt.e[n].k]);
    #pragma unroll
    for (int t = 0; t < 8; ++t) { jnh[0][t] = (__bf16)o16[t]; jnh[1][t] = (__bf16)o16[8+t]; }
  }
  __syncthreads();                     // HT reads complete -> overlay XA/C0

  { // write hidden -> XA bf16 [16j][16p][64c] + C0
    const int p2 = tid >> 5, ch = tid & 31;
    #pragma unroll
    for (int j = 0; j < 16; ++j) {
      const __bf16 gv = (j < 8) ? gph[0][j & 7] : gph[1][j & 7];
      const __bf16 jv = (j < 8) ? jnh[0][j & 7] : jnh[1][j & 7];
      *(__bf16*)(lds + XA_OFF + (((j<<4)+p2)<<7) + swz(p2, 2*ch))      = gv;
      *(__bf16*)(lds + XA_OFF + (((j<<4)+p2)<<7) + swz(p2, 2*(32+ch))) = jv;
    }
    *(__bf16*)(lds + C0_OFF + (p2<<7) + swz(p2, 2*ch))      = gph[0][0];
    *(__bf16*)(lds + C0_OFF + (p2<<7) + swz(p2, 2*(32+ch))) = jnh[0][0];
  }
  __syncthreads();

  // ---------------- phases B, C (hi-only, packed-acc) ----------------
  const int w = wv & 3, jh = wv >> 2;
  float* REDEQ = (float*)(lds + RED_OFF);        // [8][16]
  float* REDS  = REDEQ + 128;
  float* REDQ  = REDEQ + 256;
  float* GT    = (float*)(lds + GT_OFF);         // [16p][64o]

  #pragma unroll 1
  for (int stage = 0; stage < 2; ++stage) {
    const int mvb   = stage == 0 ? FB_MVB    : FB_MVC;
    const int s2mvb = stage == 0 ? FB_S2MV_B : FB_S2MV_C;
    const int s2sb  = stage == 0 ? FB_S2S_B  : FB_S2S_C;
    const int ms2sb = stage == 0 ? FB_MS2S_B : FB_MS2S_C;
    const int sab   = stage == 0 ? SA_OFF    : T1_OFF;
    const int tdst  = stage == 0 ? T1_OFF    : T2_OFF;
    const float* b_mv = stage == 0 ? gbo_b_mv : l1_b_mv;
    const float* b_s  = stage == 0 ? gbo_b_s  : l1_b_s;
    const int nt0 = 4*w + 2*jh;

    f32x4 acc[8], fac[2];
    #pragma unroll
    for (int j = 0; j < 8; ++j) acc[j] = f32x4{0.f,0.f,0.f,0.f};
    fac[0] = f32x4{0.f,0.f,0.f,0.f}; fac[1] = f32x4{0.f,0.f,0.f,0.f};

    if (jh == 0) mv_half<0>(acc, WB, lds, mvb, w, lane);
    else         mv_half<1>(acc, WB, lds, mvb, w, lane);

    if (stage == 0) {
      if (jh == 0) s_gemm<4,8>(acc[0], WB, lds, sab, s2mvb + w*2048, lane);
      #pragma unroll
      for (int i = 0; i < 2; ++i) {
        s_gemm<4,8>(fac[i], WB, lds, sab, s2sb + (nt0+i)*2048, lane);
        s_gemm<2,7>(fac[i], WB, lds, C0_OFF, ms2sb + (nt0+i)*1024, lane);
      }
    } else {
      if (jh == 0) s_gemm<8,9>(acc[0], WB, lds, sab, s2mvb + w*4096, lane);
      #pragma unroll
      for (int i = 0; i < 2; ++i) {
        s_gemm<8,9>(fac[i], WB, lds, sab, s2sb + (nt0+i)*4096, lane);
        s_gemm<2,7>(fac[i], WB, lds, C0_OFF, ms2sb + (nt0+i)*1024, lane);
      }
    }
    __syncthreads();

    if (jh == 0) {
      const float bm = b_mv[16*w + ol];
      #pragma unroll
      for (int r = 0; r < 4; ++r) acc[0][r] += bm;
    }
    #pragma unroll
    for (int i = 0; i < 2; ++i) {
      const float bs = b_s[16*(nt0+i) + ol];
      #pragma unroll
      for (int r = 0; r < 4; ++r) fac[i][r] += bs;
    }
    float sq[4], sm[4], s2[4];
    #pragma unroll
    for (int r = 0; r < 4; ++r) {
      sq[r] = (jh == 0)
        ? acc[0][r]*acc[0][r] + acc[2][r]*acc[2][r] + acc[3][r]*acc[3][r] + acc[4][r]*acc[4][r]
        : acc[0][r]*acc[0][r] + acc[1][r]*acc[1][r] + acc[2][r]*acc[2][r] + acc[6][r]*acc[6][r];
      sm[r] = fac[0][r] + fac[1][r];
      s2[r] = fac[0][r]*fac[0][r] + fac[1][r]*fac[1][r];
    }
    // pack acc -> bf16 (halves across-barrier live registers)
    bf16x8 pkr[4];
    #pragma unroll
    for (int r = 0; r < 4; ++r)
      #pragma unroll
      for (int jl = 0; jl < 8; ++jl) pkr[r][jl] = (__bf16)acc[jl][r];

    #pragma unroll
    for (int m = 1; m < 16; m <<= 1) {
      #pragma unroll
      for (int r = 0; r < 4; ++r) {
        sq[r] += __shfl_xor(sq[r], m);
        sm[r] += __shfl_xor(sm[r], m);
        s2[r] += __shfl_xor(s2[r], m);
      }
    }
    if (ol == 0) {
      #pragma unroll
      for (int r = 0; r < 4; ++r) {
        const int p = pg*4 + r;
        REDEQ[wv*16 + p] = sq[r]; REDS[wv*16 + p] = sm[r]; REDQ[wv*16 + p] = s2[r];
      }
    }
    __syncthreads();

    float rs[4], mu[4], rstd[4];
    #pragma unroll
    for (int r = 0; r < 4; ++r) {
      const int p = pg*4 + r;
      float te = 0.f, ts = 0.f, tq = 0.f;
      #pragma unroll
      for (int v2 = 0; v2 < 8; ++v2) { te += REDEQ[v2*16+p]; ts += REDS[v2*16+p]; tq += REDQ[v2*16+p]; }
      rs[r]   = 1.0f / sqrtf(fmaxf(te * (1.0f/64.0f), 0.01f));
      mu[r]   = ts * (1.0f/256.0f);
      rstd[r] = rsqrtf(tq * (1.0f/256.0f) - mu[r]*mu[r] + 1e-5f);
    }
    #pragma unroll
    for (int i = 0; i < 2; ++i) {
      #pragma unroll
      for (int r = 0; r < 4; ++r) {
        const int p = pg*4 + r, op = 16*(nt0+i) + ol;
        *(__bf16*)(lds + tdst + (p << 9) + swz(p, 2*op)) =
            (__bf16)gelu_t((fac[i][r] - mu[r]) * rstd[r]);
      }
    }
    if (jh == 0) {
      const int cnew = 16*w + ol;
      #pragma unroll
      for (int r = 0; r < 4; ++r) {
        const int p = pg*4 + r;
        const float a0n = (float)pkr[r][0] * rs[r];
        const float g   = gelu_t(a0n);
        GT[p*64 + cnew] = g;
        *(__bf16*)(lds + C0_OFF + (p<<7) + swz(p, 2*cnew)) = (__bf16)(g * a0n);
      }
    }
    __syncthreads();

    {
      const int cnew = 16*w + ol;
      float f[4];
      #pragma unroll
      for (int r = 0; r < 4; ++r) f[r] = rs[r] * GT[(pg*4+r)*64 + cnew];
      #pragma unroll
      for (int jl = 0; jl < 8; ++jl) {
        const int j = jh*8 + jl;
        #pragma unroll
        for (int r = 0; r < 4; ++r) {
          const int p = pg*4 + r;
          *(__bf16*)(lds + XA_OFF + (((j<<4)+p)<<7) + swz(p, 2*cnew)) = (__bf16)((float)pkr[r][jl] * f[r]);
        }
      }
    }
    __syncthreads();
  }

  { // ---------------- stage D: full-line mv output via LDS exchange ----------------
    f32x4 acc[8], fac2;
    #pragma unroll
    for (int j = 0; j < 8; ++j) acc[j] = f32x4{0.f,0.f,0.f,0.f};
    fac2 = f32x4{0.f,0.f,0.f,0.f};

    if (jh == 0) mv_half<0>(acc, WB, lds, FB_MVD, w, lane);
    else         mv_half<1>(acc, WB, lds, FB_MVD, w, lane);
    if (jh == 0) s_gemm<8,9>(acc[0], WB, lds, T2_OFF, FB_S2MV_D + w*4096, lane);
    const int ntd = w + 4*jh;
    s_gemm<8,9>(fac2, WB, lds, T2_OFF, FB_S2S_D + ntd*4096, lane);
    s_gemm<2,7>(fac2, WB, lds, C0_OFF, FB_MS2S_D + ntd*1024, lane);

    if (jh == 0) {
      const float bm = l2_b_mv[16*w + ol];
      #pragma unroll
      for (int r = 0; r < 4; ++r) acc[0][r] += bm;
    }
    __syncthreads();                   // all XA/T2/C0 reads complete -> XA reusable

    // jh=1 waves park blades 8-15 (f32) in XA region: [ (p*64+o)*8 + jl ] floats
    float* XF = (float*)(lds + XA_OFF);
    if (jh == 1) {
      #pragma unroll
      for (int r = 0; r < 4; ++r) {
        const int p = pg*4 + r, o = 16*w + ol;
        float* dst = XF + ((p << 6) + o) * 8;
        *(float4*)(dst)     = make_float4(acc[0][r], acc[1][r], acc[2][r], acc[3][r]);
        *(float4*)(dst + 4) = make_float4(acc[4][r], acc[5][r], acc[6][r], acc[7][r]);
      }
    }
    __syncthreads();

    // jh=0 waves write FULL 64B lines: own blades 0-7 + LDS blades 8-15
    if (jh == 0) {
      #pragma unroll
      for (int r = 0; r < 4; ++r) {
        const int p = pg*4 + r, o = 16*w + ol;
        const float* sp = XF + ((p << 6) + o) * 8;
        float* dst = out + ((size_t)(n0 + p)*64 + o)*16;
        *(float4*)(dst+0)  = make_float4(acc[0][r], acc[1][r], acc[2][r], acc[3][r]);
        *(float4*)(dst+4)  = make_float4(acc[4][r], acc[5][r], acc[6][r], acc[7][r]);
        *(float4*)(dst+8)  = *(const float4*)(sp);
        *(float4*)(dst+12) = *(const float4*)(sp + 4);
      }
    }
    { // scalar out (full-line already)
      const int od = 16*ntd + ol;
      const float bs = l2_b_s[od];
      #pragma unroll
      for (int r = 0; r < 4; ++r) {
        const int p = pg*4 + r;
        out[SOFF + (size_t)(n0 + p)*128 + od] = fac2[r] + bs;
      }
    }
  }
}

// ============================ host launch ============================
extern "C" void kernel_launch(void* const* d_in, const int* in_sizes, int n_in,
                              void* d_out, int out_size, void* d_ws, size_t ws_size,
                              hipStream_t stream) {
  const float* xin          = (const float*)d_in[0];
  const float* sinp         = (const float*)d_in[1];
  const float* gb_w_mv      = (const float*)d_in[2];
  const float* gb_w_s2mv    = (const float*)d_in[3];
  const float* gb_b_mv      = (const float*)d_in[4];
  const float* gbo_w_mv     = (const float*)d_in[5];
  const float* gbo_w_s2mv   = (const float*)d_in[6];
  const float* gbo_b_mv     = (const float*)d_in[7];
  const float* gbo_w_mvs2s  = (const float*)d_in[8];
  const float* gbo_w_s2s    = (const float*)d_in[9];
  const float* gbo_b_s      = (const float*)d_in[10];
  const float* l1_w_mv      = (const float*)d_in[11];
  const float* l1_w_s2mv    = (const float*)d_in[12];
  const float* l1_b_mv      = (const float*)d_in[13];
  const float* l1_w_mvs2s   = (const float*)d_in[14];
  const float* l1_w_s2s     = (const float*)d_in[15];
  const float* l1_b_s       = (const float*)d_in[16];
  const float* l2_w_mv      = (const float*)d_in[17];
  const float* l2_w_s2mv    = (const float*)d_in[18];
  const float* l2_b_mv      = (const float*)d_in[19];
  const float* l2_w_mvs2s   = (const float*)d_in[20];
  const float* l2_w_s2s     = (const float*)d_in[21];
  const float* l2_b_s       = (const float*)d_in[22];
  unsigned short* WBu = (unsigned short*)d_ws;
  float* out = (float*)d_out;

  prep_bf<<<(TOT_BF + 255) / 256, 256, 0, stream>>>(
      gbo_w_mv, gbo_w_s2mv, gbo_w_mvs2s, gbo_w_s2s,
      l1_w_mv, l1_w_s2mv, l1_w_mvs2s, l1_w_s2s,
      l2_w_mv, l2_w_s2mv, l2_w_mvs2s, l2_w_s2s, WBu);

  prep_ga<<<(SA_TOT + 255) / 256, 256, 0, stream>>>(gb_w_mv, gb_w_s2mv, WBu);

  fused_all<<<NPTS / 16, 512, 0, stream>>>(
      xin, sinp, gb_b_mv, gbo_b_mv, gbo_b_s, l1_b_mv, l1_b_s,
      l2_b_mv, l2_b_s, WBu, out);
}

// Round 21
// 219.270 us; speedup vs baseline: 1.7272x; 1.7270x over previous
//
#include <hip/hip_runtime.h>
#include <math.h>

typedef __bf16 bf16x8 __attribute__((ext_vector_type(8)));
typedef float  f32x4  __attribute__((ext_vector_type(4)));

// ============================ constants ============================
constexpr int NPTS = 32768;
constexpr long long SOFF = 33554432LL;        // NPTS*64*16, start of scalar outputs

// ---- bf16 fragment region (all weights), element offsets in WBu ----
constexpr int TOT_BF   = 323584;
constexpr int FB_MVB    = 0;
constexpr int FB_MVC    = 36864;
constexpr int FB_MVD    = 73728;
constexpr int FB_S2MV_B = 110592;
constexpr int FB_S2MV_C = 118784;
constexpr int FB_S2MV_D = 135168;
constexpr int FB_S2S_B  = 151552;
constexpr int FB_S2S_C  = 184320;
constexpr int FB_S2S_D  = 249856;
constexpr int FB_MS2S_B = 282624;
constexpr int FB_MS2S_C = 299008;
constexpr int FB_MS2S_D = 315392;
// stage-A frags: hi at [SAW, SAW+SA_TOT), lo at [SAW+SA_TOT, SAW+2*SA_TOT)
constexpr int SAW      = 647168;
constexpr int GAS2_OFF = 73728;
constexpr int SA_TOT   = 90112;

// ---- fused LDS layout (bytes) ----
constexpr int XA_OFF  = 0;        // bf16 [16j][16p][64c] swizzled, 32768
constexpr int HT0_OFF = 32768;    // bf16 [16p][128 rows][8j(0-7)] 16B rows, 32768
// HT1 (j8-15) overlays XA at [0,32768) after phase-A reads complete
constexpr int T1_OFF  = 36864;    // bf16 [16p][256] swizzled, 8192 (overlays HT0 post-GP/JOIN)
constexpr int T2_OFF  = 45056;    // 8192
constexpr int C0_OFF  = 53248;    // bf16 [16p][64] swizzled, 2048
constexpr int RED_OFF = 55296;    // 3 x f32[4wv][16p] = 768
constexpr int SA_OFF  = 65536;    // bf16 [16p][128] swizzled, 4096
constexpr int LDS_BYTES = 69632;  // 2 blocks/CU (LDS-bound)

// ==================== compile-time GA tables (GP/JOIN) ====================
namespace ga {
constexpr int MASK_OF[16] = {0,1,2,4,8,3,5,9,6,10,12,7,11,13,14,15};
constexpr int idx_of_mask(int m){ int r = 0; for(int i=0;i<16;++i) if(MASK_OF[i]==m) r=i; return r; }
constexpr int pcount(int x){ int c=0; while(x){ c += x&1; x >>= 1; } return c; }
constexpr int nswaps(int a,int b){ int s=0; a >>= 1; while(a){ s += pcount(a&b); a >>= 1; } return s; }
constexpr float rsign(int a,int b){ return (nswaps(a,b)&1) ? -1.0f : 1.0f; }
constexpr float dsign(int m){ return rsign(m, 15^m); }
struct Ent { int i, j, k; float s; };
struct GPT { Ent e[192]; };
constexpr GPT make_gp(){
  GPT t{}; int n=0;
  for(int i=0;i<16;++i) for(int j=0;j<16;++j){
    const int a=MASK_OF[i], b=MASK_OF[j];
    if((a & b & 1) != 0) continue;
    t.e[n].i=i; t.e[n].j=j; t.e[n].k=idx_of_mask(a^b); t.e[n].s=rsign(a,b); ++n;
  }
  return t;
}
struct JNT { Ent e[81]; };
constexpr JNT make_jn(){
  JNT t{}; int n=0;
  for(int i=0;i<16;++i) for(int j=0;j<16;++j){
    const int ci = 15 ^ MASK_OF[i], cj = 15 ^ MASK_OF[j];
    if((ci & cj) != 0) continue;
    const int mr = ci ^ cj, mk = 15 ^ mr;
    t.e[n].i=i; t.e[n].j=j; t.e[n].k=idx_of_mask(mk);
    t.e[n].s = dsign(MASK_OF[i]) * dsign(MASK_OF[j]) * rsign(ci,cj) * dsign(mk);
    ++n;
  }
  return t;
}
constexpr GPT GPt = make_gp();
constexpr JNT JNt = make_jn();
} // namespace ga

// ============================ helpers ============================
__device__ __forceinline__ float gelu_t(float x){
  const float u = 0.7978845608028654f * x * (1.0f + 0.044715f * x * x);
  return 0.5f * x * (1.0f + tanhf(u));
}
__device__ __forceinline__ int swz(int p, int byteoff){ return byteoff ^ ((p & 7) << 4); }
__device__ __forceinline__ int htaddr(int p, int o){ return (p << 11) + ((o * 16) ^ ((p & 7) << 4)); }

// ======================= prep: bcdm bf16 fragment weights =======================
__global__ void prep_bf(
    const float* __restrict__ gbo_w_mv, const float* __restrict__ gbo_w_s2mv,
    const float* __restrict__ gbo_w_mvs2s, const float* __restrict__ gbo_w_s2s,
    const float* __restrict__ l1_w_mv, const float* __restrict__ l1_w_s2mv,
    const float* __restrict__ l1_w_mvs2s, const float* __restrict__ l1_w_s2s,
    const float* __restrict__ l2_w_mv, const float* __restrict__ l2_w_s2mv,
    const float* __restrict__ l2_w_mvs2s, const float* __restrict__ l2_w_s2s,
    unsigned short* __restrict__ WBu)
{
  const int idx = blockIdx.x * 256 + threadIdx.x;
  if (idx >= TOT_BF) return;
  float v = 0.0f;
  if (idx < FB_S2MV_B) {
    const int st = idx / 36864, r2 = idx % 36864;
    const int k9 = r2 >> 12, r3 = r2 & 4095;
    const int nt = r3 >> 10, ks = (r3 >> 9) & 1, l = (r3 >> 3) & 63, e = r3 & 7;
    const int o = 16*nt + (l & 15), c = 32*ks + 8*(l >> 4) + e;
    const float* src = st==0 ? gbo_w_mv : (st==1 ? l1_w_mv : l2_w_mv);
    v = src[(o*64 + c)*9 + k9];
  } else if (idx < FB_S2S_B) {
    const float* src; int r, KS, KK;
    if (idx < FB_S2MV_C)      { r = idx - FB_S2MV_B; KS=4; KK=128; src=gbo_w_s2mv; }
    else if (idx < FB_S2MV_D) { r = idx - FB_S2MV_C; KS=8; KK=256; src=l1_w_s2mv; }
    else                      { r = idx - FB_S2MV_D; KS=8; KK=256; src=l2_w_s2mv; }
    const int per = KS*512, nt = r / per, r3 = r % per;
    const int ks = r3 >> 9, l = (r3 >> 3) & 63, e = r3 & 7;
    const int o = 16*nt + (l & 15), k = 32*ks + 8*(l >> 4) + e;
    v = src[o*KK + k];
  } else if (idx < FB_MS2S_B) {
    const float* src; int r, KS, KK;
    if (idx < FB_S2S_C)      { r = idx - FB_S2S_B; KS=4; KK=128; src=gbo_w_s2s; }
    else if (idx < FB_S2S_D) { r = idx - FB_S2S_C; KS=8; KK=256; src=l1_w_s2s; }
    else                     { r = idx - FB_S2S_D; KS=8; KK=256; src=l2_w_s2s; }
    const int per = KS*512, nt = r / per, r3 = r % per;
    const int ks = r3 >> 9, l = (r3 >> 3) & 63, e = r3 & 7;
    const int o = 16*nt + (l & 15), k = 32*ks + 8*(l >> 4) + e;
    v = src[o*KK + k];
  } else {
    const float* src; int r;
    if (idx < FB_MS2S_C)      { r = idx - FB_MS2S_B; src = gbo_w_mvs2s; }
    else if (idx < FB_MS2S_D) { r = idx - FB_MS2S_C; src = l1_w_mvs2s; }
    else                      { r = idx - FB_MS2S_D; src = l2_w_mvs2s; }
    const int nt = r >> 10, r3 = r & 1023;
    const int ks = r3 >> 9, l = (r3 >> 3) & 63, e = r3 & 7;
    const int o = 16*nt + (l & 15), k = 32*ks + 8*(l >> 4) + e;
    v = src[o*64 + k];
  }
  __bf16* WB = (__bf16*)WBu;
  const __bf16 h = (__bf16)v;
  WB[idx] = h;
  WB[TOT_BF + idx] = (__bf16)(v - (float)h);
}

// ======================= prep: stage-A bf16 fragments =======================
__global__ void prep_ga(const float* __restrict__ gb_w_mv,
                        const float* __restrict__ gb_w_s2mv,
                        unsigned short* __restrict__ WBu)
{
  const int idx = blockIdx.x * 256 + threadIdx.x;
  if (idx >= SA_TOT) return;
  float v;
  if (idx < GAS2_OFF) {                 // [9k][8nt][2ks][64l][8e]
    const int k9 = idx >> 13, r3 = idx & 8191;
    const int nt = r3 >> 10, ks = (r3 >> 9) & 1, l = (r3 >> 3) & 63, e = r3 & 7;
    const int o = 16*nt + (l & 15), c = 32*ks + 8*(l >> 4) + e;
    v = gb_w_mv[(o*64 + c)*9 + k9];
  } else {                              // [8nt][4ks][64l][8e]
    const int r = idx - GAS2_OFF;
    const int nt = r >> 11, ks = (r >> 9) & 3, l = (r >> 3) & 63, e = r & 7;
    const int o = 16*nt + (l & 15), k = 32*ks + 8*(l >> 4) + e;
    v = gb_w_s2mv[o*128 + k];
  }
  __bf16* WB = (__bf16*)WBu;
  const __bf16 h = (__bf16)v;
  WB[SAW + idx] = h;
  WB[SAW + SA_TOT + idx] = (__bf16)(v - (float)h);   // lo kept (unused)
}

// ======================= MFMA helpers =======================
template<int PASS>
__device__ __forceinline__ void ga_half(f32x4 (&acc)[8], const __bf16* __restrict__ WB,
                                        const unsigned char* lds, int nt, int lane)
{
  constexpr int GR[16] = {0,1,1,1,1,2,2,2,2,2,2,3,3,3,3,4};
  constexpr int PJ[16] = {-1,0,-1,-1,-1,2,3,4,-1,-1,-1,8,9,10,-1,14};
  constexpr int KE[16] = {0,5,0,0,0,6,6,6,0,0,0,7,7,7,0,8};
  const int pa  = lane & 15;
  const int cb0 = (lane >> 4) << 4;
  const int wl8 = lane << 3;
  #pragma unroll
  for (int jl = 0; jl < 8; ++jl) {
    const int j = PASS*8 + jl;
    #pragma unroll
    for (int ks = 0; ks < 2; ++ks) {
      bf16x8 a = *(const bf16x8*)(lds + XA_OFF + (((j<<4)+pa)<<7) + swz(pa, cb0 + (ks<<6)));
      const __bf16* bp = WB + SAW + GR[j]*8192 + (nt<<10) + (ks<<9) + wl8;
      acc[jl] = __builtin_amdgcn_mfma_f32_16x16x32_bf16(a, *(const bf16x8*)bp, acc[jl], 0, 0, 0);
    }
    if (PJ[j] >= 0) {
      #pragma unroll
      for (int ks = 0; ks < 2; ++ks) {
        bf16x8 a = *(const bf16x8*)(lds + XA_OFF + (((PJ[j]<<4)+pa)<<7) + swz(pa, cb0 + (ks<<6)));
        const __bf16* bp = WB + SAW + KE[j]*8192 + (nt<<10) + (ks<<9) + wl8;
        acc[jl] = __builtin_amdgcn_mfma_f32_16x16x32_bf16(a, *(const bf16x8*)bp, acc[jl], 0, 0, 0);
      }
    }
  }
}
template<int JH>
__device__ __forceinline__ void mv_half(f32x4 (&acc)[8], const __bf16* __restrict__ WB,
                                        const unsigned char* lds, int mvbase, int w, int lane)
{
  constexpr int GRa[2][8] = {{0,1,1,1,1,2,2,2},{2,2,2,3,3,3,3,4}};
  constexpr int PJa[2][8] = {{-1,0,-1,-1,-1,2,3,4},{-1,-1,-1,8,9,10,-1,14}};
  constexpr int KEa[2][8] = {{0,5,0,0,0,6,6,6},{0,0,0,7,7,7,0,8}};
  const int pa  = lane & 15;
  const int cb0 = (lane >> 4) << 4;
  const int wl8 = lane << 3;
  #pragma unroll
  for (int jl = 0; jl < 8; ++jl) {
    const int j = JH*8 + jl;
    #pragma unroll
    for (int ks = 0; ks < 2; ++ks) {
      bf16x8 a = *(const bf16x8*)(lds + XA_OFF + (((j<<4)+pa)<<7) + swz(pa, cb0 + (ks<<6)));
      const __bf16* bp = WB + mvbase + GRa[JH][jl]*4096 + (w<<10) + (ks<<9) + wl8;
      acc[jl] = __builtin_amdgcn_mfma_f32_16x16x32_bf16(a, *(const bf16x8*)bp, acc[jl], 0, 0, 0);
    }
    if (PJa[JH][jl] >= 0) {
      #pragma unroll
      for (int ks = 0; ks < 2; ++ks) {
        bf16x8 a = *(const bf16x8*)(lds + XA_OFF + (((PJa[JH][jl]<<4)+pa)<<7) + swz(pa, cb0 + (ks<<6)));
        const __bf16* bp = WB + mvbase + KEa[JH][jl]*4096 + (w<<10) + (ks<<9) + wl8;
        acc[jl] = __builtin_amdgcn_mfma_f32_16x16x32_bf16(a, *(const bf16x8*)bp, acc[jl], 0, 0, 0);
      }
    }
  }
}
template<int KS, int RSH>
__device__ __forceinline__ void s_gemm(f32x4& acc, const __bf16* __restrict__ WB,
                                       const unsigned char* lds, int abase, int wbase, int lane)
{
  const int pa  = lane & 15;
  const int cb0 = (lane >> 4) << 4;
  const int wl8 = lane << 3;
  #pragma unroll
  for (int ks = 0; ks < KS; ++ks) {
    bf16x8 a = *(const bf16x8*)(lds + abase + (pa << RSH) + swz(pa, cb0 + (ks << 6)));
    const __bf16* bp = WB + wbase + (ks << 9) + wl8;
    acc = __builtin_amdgcn_mfma_f32_16x16x32_bf16(a, *(const bf16x8*)bp, acc, 0, 0, 0);
  }
}

// ======================= fused_all: 256 thr / 4 waves / 16 pts =======================
// R21: two independent barrier domains per CU (2 blocks resident, LDS-bound).
// Wave wv owns o-tile [16wv,16wv+16); executes both blade-half roles
// sequentially (packed-bf16 holds). Gate now lane-local (GT + 1 barrier/stage
// removed); stage-D writes full 64B lines from registers (exchange removed).
__global__ __launch_bounds__(256, 2) void fused_all(
    const float* __restrict__ xin,  const float* __restrict__ sinp,
    const float* __restrict__ gb_b_mv,
    const float* __restrict__ gbo_b_mv, const float* __restrict__ gbo_b_s,
    const float* __restrict__ l1_b_mv,  const float* __restrict__ l1_b_s,
    const float* __restrict__ l2_b_mv,  const float* __restrict__ l2_b_s,
    const unsigned short* __restrict__ WBu,
    float* __restrict__ out)
{
  __shared__ __align__(16) unsigned char lds[LDS_BYTES];
  const __bf16* WB = (const __bf16*)WBu;
  const int tid = threadIdx.x, lane = tid & 63, wv = tid >> 6;   // wv 0..3
  const int pg = lane >> 4, ol = lane & 15;
  const int n0 = blockIdx.x * 16;

  // ---------------- stage xin -> XA, sinp -> SA ----------------
  {
    const float4* src = (const float4*)(xin + (size_t)n0 * 1024);
    #pragma unroll
    for (int q = 0; q < 16; ++q) {
      const int i = q * 256 + tid;
      const float4 v = src[i];
      const int p = i >> 8, c = (i >> 2) & 63, j0 = (i & 3) << 2;
      const float vv[4] = {v.x, v.y, v.z, v.w};
      #pragma unroll
      for (int t = 0; t < 4; ++t)
        *(__bf16*)(lds + XA_OFF + ((((j0 + t) << 4) + p) << 7) + swz(p, 2 * c)) = (__bf16)vv[t];
    }
    #pragma unroll
    for (int q = 0; q < 2; ++q) {
      const int i = q * 256 + tid;
      const float4 v = ((const float4*)(sinp + (size_t)n0 * 128))[i];
      const int p = i >> 5, k0 = (i & 31) << 2;
      const float vv[4] = {v.x, v.y, v.z, v.w};
      #pragma unroll
      for (int t = 0; t < 4; ++t)
        *(__bf16*)(lds + SA_OFF + (p << 8) + swz(p, 2 * (k0 + t))) = (__bf16)vv[t];
    }
  }
  __syncthreads();

  // ---------------- phase A: pass0 (both halves) then pass1 (both halves) ----------------
  {
    #pragma unroll
    for (int h = 0; h < 2; ++h) {     // pass 0: blades 0..7 -> HT0
      const int nt = wv + 4*h, o = 16*nt + ol;
      f32x4 acc[8];
      #pragma unroll
      for (int j = 0; j < 8; ++j) acc[j] = f32x4{0.f,0.f,0.f,0.f};
      ga_half<0>(acc, WB, lds, nt, lane);
      {
        const int pa  = lane & 15;
        const int cb0 = (lane >> 4) << 4;
        const int wl8 = lane << 3;
        #pragma unroll
        for (int ks = 0; ks < 4; ++ks) {
          bf16x8 a = *(const bf16x8*)(lds + SA_OFF + (pa << 8) + swz(pa, cb0 + (ks << 6)));
          const __bf16* bp = WB + SAW + GAS2_OFF + (nt<<11) + (ks<<9) + wl8;
          acc[0] = __builtin_amdgcn_mfma_f32_16x16x32_bf16(a, *(const bf16x8*)bp, acc[0], 0, 0, 0);
        }
        const float bm = gb_b_mv[o];
        #pragma unroll
        for (int r = 0; r < 4; ++r) acc[0][r] += bm;
      }
      #pragma unroll
      for (int r = 0; r < 4; ++r) {
        const int p = pg*4 + r;
        bf16x8 h0;
        #pragma unroll
        for (int j = 0; j < 8; ++j) h0[j] = (__bf16)acc[j][r];
        *(bf16x8*)(lds + HT0_OFF + htaddr(p, o)) = h0;
      }
    }
    bf16x8 hold[2][4];
    #pragma unroll
    for (int h = 0; h < 2; ++h) {     // pass 1: blades 8..15, hold packed
      const int nt = wv + 4*h;
      f32x4 acc[8];
      #pragma unroll
      for (int j = 0; j < 8; ++j) acc[j] = f32x4{0.f,0.f,0.f,0.f};
      ga_half<1>(acc, WB, lds, nt, lane);
      #pragma unroll
      for (int r = 0; r < 4; ++r)
        #pragma unroll
        for (int j = 0; j < 8; ++j) hold[h][r][j] = (__bf16)acc[j][r];
    }
    __syncthreads();                   // all XA reads complete
    #pragma unroll
    for (int h = 0; h < 2; ++h) {
      const int o = 16*(wv + 4*h) + ol;
      #pragma unroll
      for (int r = 0; r < 4; ++r)
        *(bf16x8*)(lds + htaddr(pg*4 + r, o)) = hold[h][r];
    }
  }
  __syncthreads();

  // ---------------- GP + JOIN (2 points per thread), packed ----------------
  bf16x8 gpk[2][2], jnk[2][2];
  {
    const int p2 = tid >> 5, ch = tid & 31;
    #pragma unroll
    for (int q = 0; q < 2; ++q) {
      const int pp = p2 + 8*q;
      float L[16], R[16], o16[16];
      auto ldrow = [&](int row, float* X){
        bf16x8 a = *(const bf16x8*)(lds + HT0_OFF + htaddr(pp, row));
        bf16x8 b = *(const bf16x8*)(lds + htaddr(pp, row));
        #pragma unroll
        for (int t = 0; t < 8; ++t) { X[t] = (float)a[t]; X[8+t] = (float)b[t]; }
      };
      ldrow(ch, L); ldrow(32 + ch, R);
      #pragma unroll
      for (int j = 0; j < 16; ++j) o16[j] = 0.0f;
      #pragma unroll
      for (int n = 0; n < 192; ++n)
        o16[ga::GPt.e[n].k] = fmaf(ga::GPt.e[n].s * L[ga::GPt.e[n].i], R[ga::GPt.e[n].j], o16[ga::GPt.e[n].k]);
      #pragma unroll
      for (int t = 0; t < 8; ++t) { gpk[q][0][t] = (__bf16)o16[t]; gpk[q][1][t] = (__bf16)o16[8+t]; }
      ldrow(64 + ch, L); ldrow(96 + ch, R);
      #pragma unroll
      for (int j = 0; j < 16; ++j) o16[j] = 0.0f;
      #pragma unroll
      for (int n = 0; n < 81; ++n)
        o16[ga::JNt.e[n].k] = fmaf(ga::JNt.e[n].s * L[ga::JNt.e[n].i], R[ga::JNt.e[n].j], o16[ga::JNt.e[n].k]);
      #pragma unroll
      for (int t = 0; t < 8; ++t) { jnk[q][0][t] = (__bf16)o16[t]; jnk[q][1][t] = (__bf16)o16[8+t]; }
    }
  }
  __syncthreads();                     // HT reads complete -> overlay XA/C0

  {
    const int p2 = tid >> 5, ch = tid & 31;
    #pragma unroll
    for (int q = 0; q < 2; ++q) {
      const int pp = p2 + 8*q;
      #pragma unroll
      for (int j = 0; j < 16; ++j) {
        const __bf16 gv = (j < 8) ? gpk[q][0][j & 7] : gpk[q][1][j & 7];
        const __bf16 jv = (j < 8) ? jnk[q][0][j & 7] : jnk[q][1][j & 7];
        *(__bf16*)(lds + XA_OFF + (((j<<4)+pp)<<7) + swz(pp, 2*ch))      = gv;
        *(__bf16*)(lds + XA_OFF + (((j<<4)+pp)<<7) + swz(pp, 2*(32+ch))) = jv;
      }
      *(__bf16*)(lds + C0_OFF + (pp<<7) + swz(pp, 2*ch))      = gpk[q][0][0];
      *(__bf16*)(lds + C0_OFF + (pp<<7) + swz(pp, 2*(32+ch))) = jnk[q][0][0];
    }
  }
  __syncthreads();

  // ---------------- phases B, C (2 barriers each) ----------------
  float* REDEQ = (float*)(lds + RED_OFF);        // [4][16]
  float* REDS  = REDEQ + 64;
  float* REDQ  = REDEQ + 128;

  #pragma unroll 1
  for (int stage = 0; stage < 2; ++stage) {
    const int mvb   = stage == 0 ? FB_MVB    : FB_MVC;
    const int s2mvb = stage == 0 ? FB_S2MV_B : FB_S2MV_C;
    const int s2sb  = stage == 0 ? FB_S2S_B  : FB_S2S_C;
    const int ms2sb = stage == 0 ? FB_MS2S_B : FB_MS2S_C;
    const int sab   = stage == 0 ? SA_OFF    : T1_OFF;
    const int tdst  = stage == 0 ? T1_OFF    : T2_OFF;
    const float* b_mv = stage == 0 ? gbo_b_mv : l1_b_mv;
    const float* b_s  = stage == 0 ? gbo_b_s  : l1_b_s;

    f32x4 fac[4];
    #pragma unroll
    for (int i = 0; i < 4; ++i) fac[i] = f32x4{0.f,0.f,0.f,0.f};
    bf16x8 pk[2][4];
    float sq[4] = {0.f,0.f,0.f,0.f};

    #pragma unroll
    for (int h = 0; h < 2; ++h) {
      f32x4 acc[8];
      #pragma unroll
      for (int j = 0; j < 8; ++j) acc[j] = f32x4{0.f,0.f,0.f,0.f};
      if (h == 0) mv_half<0>(acc, WB, lds, mvb, wv, lane);
      else        mv_half<1>(acc, WB, lds, mvb, wv, lane);
      if (h == 0) {
        if (stage == 0) s_gemm<4,8>(acc[0], WB, lds, sab, s2mvb + wv*2048, lane);
        else            s_gemm<8,9>(acc[0], WB, lds, sab, s2mvb + wv*4096, lane);
        const float bm = b_mv[16*wv + ol];
        #pragma unroll
        for (int r = 0; r < 4; ++r) acc[0][r] += bm;
      }
      const int nt0 = 4*wv + 2*h;
      #pragma unroll
      for (int i = 0; i < 2; ++i) {
        if (stage == 0) s_gemm<4,8>(fac[2*h+i], WB, lds, sab, s2sb + (nt0+i)*2048, lane);
        else            s_gemm<8,9>(fac[2*h+i], WB, lds, sab, s2sb + (nt0+i)*4096, lane);
        s_gemm<2,7>(fac[2*h+i], WB, lds, C0_OFF, ms2sb + (nt0+i)*1024, lane);
        const float bs = b_s[16*(nt0+i) + ol];
        #pragma unroll
        for (int r = 0; r < 4; ++r) fac[2*h+i][r] += bs;
      }
      #pragma unroll
      for (int r = 0; r < 4; ++r) {
        sq[r] += (h == 0)
          ? acc[0][r]*acc[0][r] + acc[2][r]*acc[2][r] + acc[3][r]*acc[3][r] + acc[4][r]*acc[4][r]
          : acc[0][r]*acc[0][r] + acc[1][r]*acc[1][r] + acc[2][r]*acc[2][r] + acc[6][r]*acc[6][r];
        #pragma unroll
        for (int jl = 0; jl < 8; ++jl) pk[h][r][jl] = (__bf16)acc[jl][r];
      }
    }
    float sm[4], s2[4];
    #pragma unroll
    for (int r = 0; r < 4; ++r) {
      sm[r] = fac[0][r]+fac[1][r]+fac[2][r]+fac[3][r];
      s2[r] = fac[0][r]*fac[0][r]+fac[1][r]*fac[1][r]+fac[2][r]*fac[2][r]+fac[3][r]*fac[3][r];
    }
    #pragma unroll
    for (int m = 1; m < 16; m <<= 1) {
      #pragma unroll
      for (int r = 0; r < 4; ++r) {
        sq[r] += __shfl_xor(sq[r], m);
        sm[r] += __shfl_xor(sm[r], m);
        s2[r] += __shfl_xor(s2[r], m);
      }
    }
    if (ol == 0) {
      #pragma unroll
      for (int r = 0; r < 4; ++r) {
        const int p = pg*4 + r;
        REDEQ[wv*16 + p] = sq[r]; REDS[wv*16 + p] = sm[r]; REDQ[wv*16 + p] = s2[r];
      }
    }
    __syncthreads();                   // (1) GEMM reads done + RED visible

    float rs[4], mu[4], rstd[4];
    #pragma unroll
    for (int r = 0; r < 4; ++r) {
      const int p = pg*4 + r;
      float te = 0.f, ts = 0.f, tq = 0.f;
      #pragma unroll
      for (int v2 = 0; v2 < 4; ++v2) { te += REDEQ[v2*16+p]; ts += REDS[v2*16+p]; tq += REDQ[v2*16+p]; }
      rs[r]   = 1.0f / sqrtf(fmaxf(te * (1.0f/64.0f), 0.01f));
      mu[r]   = ts * (1.0f/256.0f);
      rstd[r] = rsqrtf(tq * (1.0f/256.0f) - mu[r]*mu[r] + 1e-5f);
    }
    #pragma unroll
    for (int i = 0; i < 4; ++i) {
      #pragma unroll
      for (int r = 0; r < 4; ++r) {
        const int p = pg*4 + r, op = 16*(4*wv+i) + ol;
        *(__bf16*)(lds + tdst + (p << 9) + swz(p, 2*op)) =
            (__bf16)gelu_t((fac[i][r] - mu[r]) * rstd[r]);
      }
    }
    { // gate lane-local; C0 + XA writes
      const int cnew = 16*wv + ol;
      float f[4];
      #pragma unroll
      for (int r = 0; r < 4; ++r) {
        const int p = pg*4 + r;
        const float a0n = (float)pk[0][r][0] * rs[r];
        const float g   = gelu_t(a0n);
        f[r] = rs[r] * g;
        *(__bf16*)(lds + C0_OFF + (p<<7) + swz(p, 2*cnew)) = (__bf16)(g * a0n);
      }
      #pragma unroll
      for (int j = 0; j < 16; ++j) {
        #pragma unroll
        for (int r = 0; r < 4; ++r) {
          const int p = pg*4 + r;
          const float v = (float)((j < 8) ? pk[0][r][j & 7] : pk[1][r][j & 7]) * f[r];
          *(__bf16*)(lds + XA_OFF + (((j<<4)+p)<<7) + swz(p, 2*cnew)) = (__bf16)v;
        }
      }
    }
    __syncthreads();                   // (2) writes visible for next stage
  }

  // ---------------- stage D: full-line output from registers ----------------
  {
    f32x4 acc0[8], acc1[8], fac2[2];
    #pragma unroll
    for (int j = 0; j < 8; ++j) { acc0[j] = f32x4{0.f,0.f,0.f,0.f}; acc1[j] = f32x4{0.f,0.f,0.f,0.f}; }
    fac2[0] = f32x4{0.f,0.f,0.f,0.f}; fac2[1] = f32x4{0.f,0.f,0.f,0.f};

    mv_half<0>(acc0, WB, lds, FB_MVD, wv, lane);
    s_gemm<8,9>(acc0[0], WB, lds, T2_OFF, FB_S2MV_D + wv*4096, lane);
    s_gemm<8,9>(fac2[0], WB, lds, T2_OFF, FB_S2S_D + wv*4096, lane);
    s_gemm<2,7>(fac2[0], WB, lds, C0_OFF, FB_MS2S_D + wv*1024, lane);
    mv_half<1>(acc1, WB, lds, FB_MVD, wv, lane);
    s_gemm<8,9>(fac2[1], WB, lds, T2_OFF, FB_S2S_D + (wv+4)*4096, lane);
    s_gemm<2,7>(fac2[1], WB, lds, C0_OFF, FB_MS2S_D + (wv+4)*1024, lane);

    const float bm = l2_b_mv[16*wv + ol];
    #pragma unroll
    for (int r = 0; r < 4; ++r) acc0[0][r] += bm;

    #pragma unroll
    for (int r = 0; r < 4; ++r) {
      const int p = pg*4 + r, o = 16*wv + ol;
      float* dst = out + ((size_t)(n0 + p)*64 + o)*16;
      *(float4*)(dst+0)  = make_float4(acc0[0][r], acc0[1][r], acc0[2][r], acc0[3][r]);
      *(float4*)(dst+4)  = make_float4(acc0[4][r], acc0[5][r], acc0[6][r], acc0[7][r]);
      *(float4*)(dst+8)  = make_float4(acc1[0][r], acc1[1][r], acc1[2][r], acc1[3][r]);
      *(float4*)(dst+12) = make_float4(acc1[4][r], acc1[5][r], acc1[6][r], acc1[7][r]);
    }
    #pragma unroll
    for (int q = 0; q < 2; ++q) {
      const int od = 16*(wv + 4*q) + ol;
      const float bs = l2_b_s[od];
      #pragma unroll
      for (int r = 0; r < 4; ++r) {
        const int p = pg*4 + r;
        out[SOFF + (size_t)(n0 + p)*128 + od] = fac2[q][r] + bs;
      }
    }
  }
}

// ============================ host launch ============================
extern "C" void kernel_launch(void* const* d_in, const int* in_sizes, int n_in,
                              void* d_out, int out_size, void* d_ws, size_t ws_size,
                              hipStream_t stream) {
  const float* xin          = (const float*)d_in[0];
  const float* sinp         = (const float*)d_in[1];
  const float* gb_w_mv      = (const float*)d_in[2];
  const float* gb_w_s2mv    = (const float*)d_in[3];
  const float* gb_b_mv      = (const float*)d_in[4];
  const float* gbo_w_mv     = (const float*)d_in[5];
  const float* gbo_w_s2mv   = (const float*)d_in[6];
  const float* gbo_b_mv     = (const float*)d_in[7];
  const float* gbo_w_mvs2s  = (const float*)d_in[8];
  const float* gbo_w_s2s    = (const float*)d_in[9];
  const float* gbo_b_s      = (const float*)d_in[10];
  const float* l1_w_mv      = (const float*)d_in[11];
  const float* l1_w_s2mv    = (const float*)d_in[12];
  const float* l1_b_mv      = (const float*)d_in[13];
  const float* l1_w_mvs2s   = (const float*)d_in[14];
  const float* l1_w_s2s     = (const float*)d_in[15];
  const float* l1_b_s       = (const float*)d_in[16];
  const float* l2_w_mv      = (const float*)d_in[17];
  const float* l2_w_s2mv    = (const float*)d_in[18];
  const float* l2_b_mv      = (const float*)d_in[19];
  const float* l2_w_mvs2s   = (const float*)d_in[20];
  const float* l2_w_s2s     = (const float*)d_in[21];
  const float* l2_b_s       = (const float*)d_in[22];
  unsigned short* WBu = (unsigned short*)d_ws;
  float* out = (float*)d_out;

  prep_bf<<<(TOT_BF + 255) / 256, 256, 0, stream>>>(
      gbo_w_mv, gbo_w_s2mv, gbo_w_mvs2s, gbo_w_s2s,
      l1_w_mv, l1_w_s2mv, l1_w_mvs2s, l1_w_s2s,
      l2_w_mv, l2_w_s2mv, l2_w_mvs2s, l2_w_s2s, WBu);

  prep_ga<<<(SA_TOT + 255) / 256, 256, 0, stream>>>(gb_w_mv, gb_w_s2mv, WBu);

  fused_all<<<NPTS / 16, 256, 0, stream>>>(
      xin, sinp, gb_b_mv, gbo_b_mv, gbo_b_s, l1_b_mv, l1_b_s,
      l2_b_mv, l2_b_s, WBu, out);
}